// Round 2
// baseline (100.597 us; speedup 1.0000x reference)
//
#include <hip/hip_runtime.h>

#define NPART 4096
#define DIM 32
#define TJ 64

// ---------------------------------------------------------------------------
// m[r] = ||x_r||^2 * 0.5 / ls^2   (pre-scaled norms)
__global__ __launch_bounds__(256) void svgd_norms_kernel(const float* __restrict__ X,
                                                         const float* __restrict__ ls,
                                                         float* __restrict__ m) {
  int row = blockIdx.x * 256 + threadIdx.x;
  const float4* xr = reinterpret_cast<const float4*>(X + (size_t)row * DIM);
  float d0 = 0.f, d1 = 0.f, d2 = 0.f, d3 = 0.f;
#pragma unroll
  for (int q = 0; q < 8; ++q) {
    float4 a = xr[q];
    d0 = fmaf(a.x, a.x, d0);
    d1 = fmaf(a.y, a.y, d1);
    d2 = fmaf(a.z, a.z, d2);
    d3 = fmaf(a.w, a.w, d3);
  }
  float lsv = ls[0];
  float inv = 1.f / (lsv * lsv);
  m[row] = ((d0 + d1) + (d2 + d3)) * (0.5f * inv);
}

// ---------------------------------------------------------------------------
// One thread per row i. x_j is read through WAVE-UNIFORM addresses so the
// compiler emits s_load (SGPR broadcast) — no LDS, no per-lane VMEM in the
// inner loop. arg = dot*inv - m_i - m_j ; k = exp(arg).
__global__ __launch_bounds__(256, 4) void svgd_main_kernel(
    const float* __restrict__ X, const float* __restrict__ ls,
    const float* __restrict__ m, float* __restrict__ pT,
    float* __restrict__ pS, int jchunk) {
  const int tid = threadIdx.x;
  const int row = blockIdx.x * 256 + tid;

  const float lsv = ls[0];
  const float inv = 1.f / (lsv * lsv);

  float4 xv[8];
  const float4* xr = reinterpret_cast<const float4*>(X + (size_t)row * DIM);
#pragma unroll
  for (int q = 0; q < 8; ++q) xv[q] = xr[q];
  const float mi = m[row];

  float acc[DIM];
#pragma unroll
  for (int d = 0; d < DIM; ++d) acc[d] = 0.f;
  float S = 0.f;

  const int j0 = blockIdx.y * jchunk;
  const int j1 = j0 + jchunk;
#pragma unroll 2
  for (int j = j0; j < j1; ++j) {
    const float* __restrict__ xj = X + (size_t)j * DIM;  // uniform -> s_load
    const float mj = m[j];                               // uniform -> s_load
    float d0 = 0.f, d1 = 0.f, d2 = 0.f, d3 = 0.f;
#pragma unroll
    for (int q = 0; q < 8; ++q) {
      d0 = fmaf(xv[q].x, xj[4 * q + 0], d0);
      d1 = fmaf(xv[q].y, xj[4 * q + 1], d1);
      d2 = fmaf(xv[q].z, xj[4 * q + 2], d2);
      d3 = fmaf(xv[q].w, xj[4 * q + 3], d3);
    }
    float dot = (d0 + d1) + (d2 + d3);
    float k = __expf(fmaf(dot, inv, -(mi + mj)));
    S += k;
#pragma unroll
    for (int d = 0; d < DIM; ++d) acc[d] = fmaf(k, xj[d], acc[d]);
  }

  float4* outT = reinterpret_cast<float4*>(pT + ((size_t)blockIdx.y * NPART + row) * DIM);
#pragma unroll
  for (int q = 0; q < 8; ++q)
    outT[q] = make_float4(acc[4 * q], acc[4 * q + 1], acc[4 * q + 2], acc[4 * q + 3]);
  pS[(size_t)blockIdx.y * NPART + row] = S;
}

// ---------------------------------------------------------------------------
// out[i,d] = (inv*S_i*x[i,d] - (1+inv)*T_i[d]) / N   (float4 per thread)
__global__ __launch_bounds__(128) void svgd_reduce_kernel(
    const float* __restrict__ X, const float* __restrict__ ls,
    const float* __restrict__ pT, const float* __restrict__ pS, int nsplit,
    float* __restrict__ out) {
  int t = blockIdx.x * 128 + threadIdx.x;  // over N*DIM/4 float4s
  int row = t >> 3;
  const float4* pT4 = reinterpret_cast<const float4*>(pT);
  float4 T = make_float4(0.f, 0.f, 0.f, 0.f);
  float S = 0.f;
  for (int s = 0; s < nsplit; ++s) {
    float4 v = pT4[(size_t)s * (NPART * DIM / 4) + t];
    T.x += v.x; T.y += v.y; T.z += v.z; T.w += v.w;
    S += pS[(size_t)s * NPART + row];
  }
  const float lsv = ls[0];
  const float inv = 1.f / (lsv * lsv);
  const float c1 = inv * S * (1.f / NPART);
  const float c2 = (1.f + inv) * (1.f / NPART);
  float4 x = reinterpret_cast<const float4*>(X)[t];
  float4 r;
  r.x = c1 * x.x - c2 * T.x;
  r.y = c1 * x.y - c2 * T.y;
  r.z = c1 * x.z - c2 * T.z;
  r.w = c1 * x.w - c2 * T.w;
  reinterpret_cast<float4*>(out)[t] = r;
}

// ---------------------------------------------------------------------------
// Fallback if workspace is too small: single pass, LDS tiles, writes out.
__global__ __launch_bounds__(256) void svgd_direct_kernel(const float* __restrict__ X,
                                                          const float* __restrict__ ls,
                                                          float* __restrict__ out) {
  __shared__ float4 sX[TJ * 8];
  const int tid = threadIdx.x;
  const int row = blockIdx.x * 256 + tid;
  const float lsv = ls[0];
  const float ls2 = lsv * lsv;
  const float inv2 = 0.5f / ls2;
  float4 xi[8];
  const float4* xr = reinterpret_cast<const float4*>(X + (size_t)row * DIM);
#pragma unroll
  for (int q = 0; q < 8; ++q) xi[q] = xr[q];
  float4 acc[8];
#pragma unroll
  for (int q = 0; q < 8; ++q) acc[q] = make_float4(0.f, 0.f, 0.f, 0.f);
  float S = 0.f;
  for (int jb = 0; jb < NPART; jb += TJ) {
    __syncthreads();
    const float4* src = reinterpret_cast<const float4*>(X + (size_t)jb * DIM);
    for (int t = tid; t < TJ * 8; t += 256) sX[t] = src[t];
    __syncthreads();
    for (int t = 0; t < TJ; ++t) {
      const float4* xj = &sX[t * 8];
      float4 v[8];
      float d0 = 0.f, d1 = 0.f, d2 = 0.f, d3 = 0.f;
#pragma unroll
      for (int q = 0; q < 8; ++q) {
        v[q] = xj[q];
        float ax = xi[q].x - v[q].x; d0 = fmaf(ax, ax, d0);
        float ay = xi[q].y - v[q].y; d1 = fmaf(ay, ay, d1);
        float az = xi[q].z - v[q].z; d2 = fmaf(az, az, d2);
        float aw = xi[q].w - v[q].w; d3 = fmaf(aw, aw, d3);
      }
      float k = __expf(-((d0 + d1) + (d2 + d3)) * inv2);
      S += k;
#pragma unroll
      for (int q = 0; q < 8; ++q) {
        acc[q].x = fmaf(k, v[q].x, acc[q].x);
        acc[q].y = fmaf(k, v[q].y, acc[q].y);
        acc[q].z = fmaf(k, v[q].z, acc[q].z);
        acc[q].w = fmaf(k, v[q].w, acc[q].w);
      }
    }
  }
  const float inv = 1.f / ls2;
  const float c1 = inv * S;
  const float c2 = 1.f + inv;
  float4* o = reinterpret_cast<float4*>(out + (size_t)row * DIM);
#pragma unroll
  for (int q = 0; q < 8; ++q) {
    float4 r;
    r.x = (c1 * xi[q].x - c2 * acc[q].x) * (1.f / NPART);
    r.y = (c1 * xi[q].y - c2 * acc[q].y) * (1.f / NPART);
    r.z = (c1 * xi[q].z - c2 * acc[q].z) * (1.f / NPART);
    r.w = (c1 * xi[q].w - c2 * acc[q].w) * (1.f / NPART);
    o[q] = r;
  }
}

// ---------------------------------------------------------------------------
extern "C" void kernel_launch(void* const* d_in, const int* in_sizes, int n_in,
                              void* d_out, int out_size, void* d_ws, size_t ws_size,
                              hipStream_t stream) {
  const float* X = (const float*)d_in[0];
  const float* ls = (const float*)d_in[1];
  float* out = (float*)d_out;
  float* ws = (float*)d_ws;

  // ws bytes needed for nsplit n: 4*(4096 + n*4096*32 + n*4096) = 16384*(1+33n)
  int nsplit = 64;
  while (nsplit > 1 && (size_t)16384 * (size_t)(1 + 33 * nsplit) > ws_size) nsplit >>= 1;

  if ((size_t)16384 * 34 > ws_size) {
    svgd_direct_kernel<<<NPART / 256, 256, 0, stream>>>(X, ls, out);
    return;
  }

  float* m = ws;
  float* pT = ws + NPART;
  float* pS = pT + (size_t)nsplit * NPART * DIM;

  svgd_norms_kernel<<<NPART / 256, 256, 0, stream>>>(X, ls, m);
  dim3 grid(NPART / 256, nsplit);
  svgd_main_kernel<<<grid, 256, 0, stream>>>(X, ls, m, pT, pS, NPART / nsplit);
  svgd_reduce_kernel<<<(NPART * DIM / 4) / 128, 128, 0, stream>>>(X, ls, pT, pS, nsplit, out);
}

// Round 3
// 50.567 us; speedup vs baseline: 1.9894x; 1.9894x over previous
//
#include <hip/hip_runtime.h>

#define NPART 4096
#define DIM 32

typedef _Float16 f16x8 __attribute__((ext_vector_type(8)));
typedef _Float16 f16x4 __attribute__((ext_vector_type(4)));
typedef float f32x4 __attribute__((ext_vector_type(4)));

// ---------------------------------------------------------------------------
// m2[r] = ||x_r||^2 * 0.5 / ls^2
__global__ __launch_bounds__(256) void svgd_norms_kernel(const float* __restrict__ X,
                                                         const float* __restrict__ ls,
                                                         float* __restrict__ m2) {
  int row = blockIdx.x * 256 + threadIdx.x;
  const float4* xr = reinterpret_cast<const float4*>(X + (size_t)row * DIM);
  float d0 = 0.f, d1 = 0.f, d2 = 0.f, d3 = 0.f;
#pragma unroll
  for (int q = 0; q < 8; ++q) {
    float4 a = xr[q];
    d0 = fmaf(a.x, a.x, d0);
    d1 = fmaf(a.y, a.y, d1);
    d2 = fmaf(a.z, a.z, d2);
    d3 = fmaf(a.w, a.w, d3);
  }
  float lsv = ls[0];
  float inv = 1.f / (lsv * lsv);
  m2[row] = ((d0 + d1) + (d2 + d3)) * (0.5f * inv);
}

// ---------------------------------------------------------------------------
// MFMA fused kernel. Wave handles a 16-row i-tile; loop over j in steps of 16.
// GEMM1: C1[j][i] = X_j . X_i^T  (3-pass fp16 split for fp32-grade dots)
// epilogue: k = exp(dot*inv - m2i - m2j)  (fp32 VALU)
// GEMM2: T[i][d] += K[i][j] . X[j][d]  (fp16 single pass, 2 d-halves)
__global__ __launch_bounds__(256, 6) void svgd_mfma_kernel(
    const float* __restrict__ X, const float* __restrict__ ls,
    const float* __restrict__ m2, float* __restrict__ pT,
    float* __restrict__ pS, int jchunk) {
  const int tid = threadIdx.x;
  const int lane = tid & 63;
  const int g = lane >> 4;    // 0..3
  const int li = lane & 15;   // 0..15
  const int wave = tid >> 6;  // 0..3
  const int i0 = blockIdx.x * 64 + wave * 16;

  const float lsv = ls[0];
  const float si = 1.f / (lsv * lsv);

  const float4* X4 = reinterpret_cast<const float4*>(X);

  // B1 fragment (X_i^T): lane -> col i = li, k(d) in {4g..4g+3} U {16+4g..16+4g+3}
  float4 xa = X4[(size_t)(i0 + li) * 8 + g];
  float4 xb = X4[(size_t)(i0 + li) * 8 + 4 + g];
  f16x8 bh, bl;
  {
    float t[8] = {xa.x, xa.y, xa.z, xa.w, xb.x, xb.y, xb.z, xb.w};
#pragma unroll
    for (int e = 0; e < 8; ++e) {
      _Float16 h = (_Float16)t[e];
      bh[e] = h;
      bl[e] = (_Float16)(t[e] - (float)h);
    }
  }
  const float mi2 = m2[i0 + li];

  f32x4 c2a = {0.f, 0.f, 0.f, 0.f};
  f32x4 c2b = {0.f, 0.f, 0.f, 0.f};
  float Sp = 0.f;

  const int jbase = blockIdx.y * jchunk;
  for (int js = 0; js < jchunk; js += 16) {
    const int j0 = jbase + js;

    // A1 fragment (X_j): lane -> row j = li, same k(d) map as B1
    float4 ya = X4[(size_t)(j0 + li) * 8 + g];
    float4 yb = X4[(size_t)(j0 + li) * 8 + 4 + g];
    f16x8 ah, al;
    {
      float t[8] = {ya.x, ya.y, ya.z, ya.w, yb.x, yb.y, yb.z, yb.w};
#pragma unroll
      for (int e = 0; e < 8; ++e) {
        _Float16 h = (_Float16)t[e];
        ah[e] = h;
        al[e] = (_Float16)(t[e] - (float)h);
      }
    }
    float4 mj4 = reinterpret_cast<const float4*>(m2)[(j0 >> 2) + g];

    f32x4 c1 = {0.f, 0.f, 0.f, 0.f};
    c1 = __builtin_amdgcn_mfma_f32_16x16x32_f16(ah, bh, c1, 0, 0, 0);
    c1 = __builtin_amdgcn_mfma_f32_16x16x32_f16(al, bh, c1, 0, 0, 0);
    c1 = __builtin_amdgcn_mfma_f32_16x16x32_f16(ah, bl, c1, 0, 0, 0);

    // epilogue: k = exp(dot/ls^2 - mi - mj); C1 reg r holds (i=li, j=4g+r)
    f16x4 a2;
    float mj[4] = {mj4.x, mj4.y, mj4.z, mj4.w};
#pragma unroll
    for (int r = 0; r < 4; ++r) {
      float arg = fmaf(c1[r], si, -(mi2 + mj[r]));
      float k = __expf(arg);
      Sp += k;
      a2[r] = (_Float16)k;
    }

    // B2 fragments: X[j0+4g+e][li] and [16+li]
    f16x4 b2a, b2b;
#pragma unroll
    for (int e = 0; e < 4; ++e) {
      b2a[e] = (_Float16)X[(size_t)(j0 + 4 * g + e) * DIM + li];
      b2b[e] = (_Float16)X[(size_t)(j0 + 4 * g + e) * DIM + 16 + li];
    }
    c2a = __builtin_amdgcn_mfma_f32_16x16x16f16(a2, b2a, c2a, 0, 0, 0);
    c2b = __builtin_amdgcn_mfma_f32_16x16x16f16(a2, b2b, c2b, 0, 0, 0);
  }

  // store T: C2 reg r holds (i = i0+4g+r, d = li / 16+li)
  float* base = pT + ((size_t)blockIdx.y * NPART + i0) * DIM;
#pragma unroll
  for (int r = 0; r < 4; ++r) {
    base[(4 * g + r) * DIM + li] = c2a[r];
    base[(4 * g + r) * DIM + 16 + li] = c2b[r];
  }
  // S: lane (g,li) reg r holds k(i=li, j=4g+r)-partials; reduce across g
  Sp += __shfl_xor(Sp, 16, 64);
  Sp += __shfl_xor(Sp, 32, 64);
  if (g == 0) pS[(size_t)blockIdx.y * NPART + i0 + li] = Sp;
}

// ---------------------------------------------------------------------------
// out[i,d] = (inv*S_i*x[i,d] - (1+inv)*T_i[d]) / N
__global__ __launch_bounds__(128) void svgd_reduce_kernel(
    const float* __restrict__ X, const float* __restrict__ ls,
    const float* __restrict__ pT, const float* __restrict__ pS, int nsplit,
    float* __restrict__ out) {
  int t = blockIdx.x * 128 + threadIdx.x;  // over N*DIM/4 float4s
  int row = t >> 3;
  const float4* pT4 = reinterpret_cast<const float4*>(pT);
  float4 T = make_float4(0.f, 0.f, 0.f, 0.f);
  float S = 0.f;
  for (int s = 0; s < nsplit; ++s) {
    float4 v = pT4[(size_t)s * (NPART * DIM / 4) + t];
    T.x += v.x; T.y += v.y; T.z += v.z; T.w += v.w;
    S += pS[(size_t)s * NPART + row];
  }
  const float lsv = ls[0];
  const float inv = 1.f / (lsv * lsv);
  const float c1 = inv * S * (1.f / NPART);
  const float c2 = (1.f + inv) * (1.f / NPART);
  float4 x = reinterpret_cast<const float4*>(X)[t];
  float4 r;
  r.x = c1 * x.x - c2 * T.x;
  r.y = c1 * x.y - c2 * T.y;
  r.z = c1 * x.z - c2 * T.z;
  r.w = c1 * x.w - c2 * T.w;
  reinterpret_cast<float4*>(out)[t] = r;
}

// ---------------------------------------------------------------------------
// Fallback if workspace is too small: single pass fp32, LDS tiles, writes out.
#define TJ 64
__global__ __launch_bounds__(256) void svgd_direct_kernel(const float* __restrict__ X,
                                                          const float* __restrict__ ls,
                                                          float* __restrict__ out) {
  __shared__ float4 sX[TJ * 8];
  const int tid = threadIdx.x;
  const int row = blockIdx.x * 256 + tid;
  const float lsv = ls[0];
  const float ls2 = lsv * lsv;
  const float inv2 = 0.5f / ls2;
  float4 xi[8];
  const float4* xr = reinterpret_cast<const float4*>(X + (size_t)row * DIM);
#pragma unroll
  for (int q = 0; q < 8; ++q) xi[q] = xr[q];
  float4 acc[8];
#pragma unroll
  for (int q = 0; q < 8; ++q) acc[q] = make_float4(0.f, 0.f, 0.f, 0.f);
  float S = 0.f;
  for (int jb = 0; jb < NPART; jb += TJ) {
    __syncthreads();
    const float4* src = reinterpret_cast<const float4*>(X + (size_t)jb * DIM);
    for (int t = tid; t < TJ * 8; t += 256) sX[t] = src[t];
    __syncthreads();
    for (int t = 0; t < TJ; ++t) {
      const float4* xj = &sX[t * 8];
      float4 v[8];
      float d0 = 0.f, d1 = 0.f, d2 = 0.f, d3 = 0.f;
#pragma unroll
      for (int q = 0; q < 8; ++q) {
        v[q] = xj[q];
        float ax = xi[q].x - v[q].x; d0 = fmaf(ax, ax, d0);
        float ay = xi[q].y - v[q].y; d1 = fmaf(ay, ay, d1);
        float az = xi[q].z - v[q].z; d2 = fmaf(az, az, d2);
        float aw = xi[q].w - v[q].w; d3 = fmaf(aw, aw, d3);
      }
      float k = __expf(-((d0 + d1) + (d2 + d3)) * inv2);
      S += k;
#pragma unroll
      for (int q = 0; q < 8; ++q) {
        acc[q].x = fmaf(k, v[q].x, acc[q].x);
        acc[q].y = fmaf(k, v[q].y, acc[q].y);
        acc[q].z = fmaf(k, v[q].z, acc[q].z);
        acc[q].w = fmaf(k, v[q].w, acc[q].w);
      }
    }
  }
  const float inv = 1.f / ls2;
  const float c1 = inv * S;
  const float c2 = 1.f + inv;
  float4* o = reinterpret_cast<float4*>(out + (size_t)row * DIM);
#pragma unroll
  for (int q = 0; q < 8; ++q) {
    float4 r;
    r.x = (c1 * xi[q].x - c2 * acc[q].x) * (1.f / NPART);
    r.y = (c1 * xi[q].y - c2 * acc[q].y) * (1.f / NPART);
    r.z = (c1 * xi[q].z - c2 * acc[q].z) * (1.f / NPART);
    r.w = (c1 * xi[q].w - c2 * acc[q].w) * (1.f / NPART);
    o[q] = r;
  }
}

// ---------------------------------------------------------------------------
extern "C" void kernel_launch(void* const* d_in, const int* in_sizes, int n_in,
                              void* d_out, int out_size, void* d_ws, size_t ws_size,
                              hipStream_t stream) {
  const float* X = (const float*)d_in[0];
  const float* ls = (const float*)d_in[1];
  float* out = (float*)d_out;
  float* ws = (float*)d_ws;

  // ws bytes for nsplit n: 4*(4096 + n*4096*32 + n*4096) = 16384*(1+33n)
  int nsplit = 32;
  while (nsplit > 1 && (size_t)16384 * (size_t)(1 + 33 * nsplit) > ws_size) nsplit >>= 1;

  if ((size_t)16384 * 34 > ws_size) {
    svgd_direct_kernel<<<NPART / 256, 256, 0, stream>>>(X, ls, out);
    return;
  }

  float* m2 = ws;
  float* pT = ws + NPART;
  float* pS = pT + (size_t)nsplit * NPART * DIM;

  svgd_norms_kernel<<<NPART / 256, 256, 0, stream>>>(X, ls, m2);
  dim3 grid(NPART / 64, nsplit);
  svgd_mfma_kernel<<<grid, 256, 0, stream>>>(X, ls, m2, pT, pS, NPART / nsplit);
  svgd_reduce_kernel<<<(NPART * DIM / 4) / 128, 128, 0, stream>>>(X, ls, pT, pS, nsplit, out);
}

// Round 4
// 42.647 us; speedup vs baseline: 2.3588x; 1.1857x over previous
//
#include <hip/hip_runtime.h>

#define NPART 4096
#define DIM 32

typedef _Float16 f16x8 __attribute__((ext_vector_type(8)));
typedef _Float16 f16x4 __attribute__((ext_vector_type(4)));
typedef float f32x4 __attribute__((ext_vector_type(4)));

// ---------------------------------------------------------------------------
// Prep: m2[r] = ||x_r||^2 * 0.5/ls^2 ; XhP/XlP = hi/lo fp16 split of X in
// MFMA-fragment element order (g*8+e -> d = e<4 ? 4g+e : 16+4g+(e-4));
// XT[d][j] = (f16)X[j][d]  (transposed, for GEMM2 B fragments).
__global__ __launch_bounds__(256) void svgd_prep_kernel(
    const float* __restrict__ X, const float* __restrict__ ls,
    float* __restrict__ m2, _Float16* __restrict__ XhP,
    _Float16* __restrict__ XlP, _Float16* __restrict__ XT) {
  const int row = blockIdx.x * 256 + threadIdx.x;
  float v[DIM];
  const float4* xr = reinterpret_cast<const float4*>(X + (size_t)row * DIM);
#pragma unroll
  for (int q = 0; q < 8; ++q) {
    float4 a = xr[q];
    v[4 * q + 0] = a.x; v[4 * q + 1] = a.y; v[4 * q + 2] = a.z; v[4 * q + 3] = a.w;
  }
  float n = 0.f;
#pragma unroll
  for (int d = 0; d < DIM; ++d) n = fmaf(v[d], v[d], n);
  const float lsv = ls[0];
  const float inv = 1.f / (lsv * lsv);
  m2[row] = n * (0.5f * inv);

  _Float16 h[DIM], l[DIM];
#pragma unroll
  for (int d = 0; d < DIM; ++d) {
    h[d] = (_Float16)v[d];
    l[d] = (_Float16)(v[d] - (float)h[d]);
  }
#pragma unroll
  for (int g = 0; g < 4; ++g) {
    f16x8 ph, pl;
#pragma unroll
    for (int e = 0; e < 8; ++e) {
      int d = (e < 4) ? (4 * g + e) : (16 + 4 * g + (e - 4));
      ph[e] = h[d];
      pl[e] = l[d];
    }
    *reinterpret_cast<f16x8*>(XhP + (size_t)row * DIM + g * 8) = ph;
    *reinterpret_cast<f16x8*>(XlP + (size_t)row * DIM + g * 8) = pl;
  }
#pragma unroll
  for (int d = 0; d < DIM; ++d) XT[(size_t)d * NPART + row] = h[d];
}

// ---------------------------------------------------------------------------
// MFMA kernel. Wave owns TWO 16-row i-tiles (32 i-rows); loops j in steps of
// 16. All operands preconverted: inner loop = 4 loads + 10 MFMA + 8-exp epi.
__global__ __launch_bounds__(256, 4) void svgd_mfma_kernel(
    const _Float16* __restrict__ XhP, const _Float16* __restrict__ XlP,
    const _Float16* __restrict__ XT, const float* __restrict__ ls,
    const float* __restrict__ m2, float* __restrict__ pT,
    float* __restrict__ pS, int jchunk) {
  const int tid = threadIdx.x;
  const int lane = tid & 63;
  const int g = lane >> 4;    // 0..3
  const int li = lane & 15;   // 0..15
  const int wave = tid >> 6;  // 0..3
  const int i0 = blockIdx.x * 128 + wave * 32;

  const float lsv = ls[0];
  const float si = 1.f / (lsv * lsv);

  // B1 fragments for 2 i-tiles
  f16x8 bh[2], bl[2];
  float mi2[2];
#pragma unroll
  for (int it = 0; it < 2; ++it) {
    const int r = i0 + it * 16 + li;
    bh[it] = *reinterpret_cast<const f16x8*>(XhP + (size_t)r * DIM + g * 8);
    bl[it] = *reinterpret_cast<const f16x8*>(XlP + (size_t)r * DIM + g * 8);
    mi2[it] = m2[r];
  }

  f32x4 c2a[2] = {{0.f, 0.f, 0.f, 0.f}, {0.f, 0.f, 0.f, 0.f}};
  f32x4 c2b[2] = {{0.f, 0.f, 0.f, 0.f}, {0.f, 0.f, 0.f, 0.f}};
  float Sp[2] = {0.f, 0.f};

  const int jbase = blockIdx.y * jchunk;
  const int niter = jchunk >> 4;
#pragma unroll 2
  for (int itr = 0; itr < niter; ++itr) {
    const int j0 = jbase + itr * 16;
    // A1 fragments (X_j hi/lo), fragment-order preconverted
    f16x8 ah = *reinterpret_cast<const f16x8*>(XhP + (size_t)(j0 + li) * DIM + g * 8);
    f16x8 al = *reinterpret_cast<const f16x8*>(XlP + (size_t)(j0 + li) * DIM + g * 8);
    // B2 fragments: XT[d=li][j0+4g+e], XT[d=16+li][j0+4g+e]
    f16x4 b2a = *reinterpret_cast<const f16x4*>(XT + (size_t)li * NPART + j0 + 4 * g);
    f16x4 b2b = *reinterpret_cast<const f16x4*>(XT + (size_t)(16 + li) * NPART + j0 + 4 * g);
    float4 mj4 = *reinterpret_cast<const float4*>(m2 + j0 + 4 * g);
    float mj[4] = {mj4.x, mj4.y, mj4.z, mj4.w};

#pragma unroll
    for (int it = 0; it < 2; ++it) {
      f32x4 c1 = {0.f, 0.f, 0.f, 0.f};
      c1 = __builtin_amdgcn_mfma_f32_16x16x32_f16(ah, bh[it], c1, 0, 0, 0);
      c1 = __builtin_amdgcn_mfma_f32_16x16x32_f16(al, bh[it], c1, 0, 0, 0);
      c1 = __builtin_amdgcn_mfma_f32_16x16x32_f16(ah, bl[it], c1, 0, 0, 0);
      // k = exp(dot*si - mi - mj); C1 reg r = (i=li, j=4g+r)
      f16x4 a2;
#pragma unroll
      for (int r = 0; r < 4; ++r) {
        float k = __expf(fmaf(c1[r], si, -(mi2[it] + mj[r])));
        Sp[it] += k;
        a2[r] = (_Float16)k;
      }
      c2a[it] = __builtin_amdgcn_mfma_f32_16x16x16f16(a2, b2a, c2a[it], 0, 0, 0);
      c2b[it] = __builtin_amdgcn_mfma_f32_16x16x16f16(a2, b2b, c2b[it], 0, 0, 0);
    }
  }

  // store T: C2 reg r = (i = base+4g+r, d = li / 16+li)
#pragma unroll
  for (int it = 0; it < 2; ++it) {
    float* base = pT + ((size_t)blockIdx.y * NPART + i0 + it * 16) * DIM;
#pragma unroll
    for (int r = 0; r < 4; ++r) {
      base[(4 * g + r) * DIM + li] = c2a[it][r];
      base[(4 * g + r) * DIM + 16 + li] = c2b[it][r];
    }
    float s = Sp[it];
    s += __shfl_xor(s, 16, 64);
    s += __shfl_xor(s, 32, 64);
    if (g == 0) pS[(size_t)blockIdx.y * NPART + i0 + it * 16 + li] = s;
  }
}

// ---------------------------------------------------------------------------
// out[i,d] = (inv*S_i*x[i,d] - (1+inv)*T_i[d]) / N
__global__ __launch_bounds__(128) void svgd_reduce_kernel(
    const float* __restrict__ X, const float* __restrict__ ls,
    const float* __restrict__ pT, const float* __restrict__ pS, int nsplit,
    float* __restrict__ out) {
  int t = blockIdx.x * 128 + threadIdx.x;  // over N*DIM/4 float4s
  int row = t >> 3;
  const float4* pT4 = reinterpret_cast<const float4*>(pT);
  float4 T = make_float4(0.f, 0.f, 0.f, 0.f);
  float S = 0.f;
  for (int s = 0; s < nsplit; ++s) {
    float4 v = pT4[(size_t)s * (NPART * DIM / 4) + t];
    T.x += v.x; T.y += v.y; T.z += v.z; T.w += v.w;
    S += pS[(size_t)s * NPART + row];
  }
  const float lsv = ls[0];
  const float inv = 1.f / (lsv * lsv);
  const float c1 = inv * S * (1.f / NPART);
  const float c2 = (1.f + inv) * (1.f / NPART);
  float4 x = reinterpret_cast<const float4*>(X)[t];
  float4 r;
  r.x = c1 * x.x - c2 * T.x;
  r.y = c1 * x.y - c2 * T.y;
  r.z = c1 * x.z - c2 * T.z;
  r.w = c1 * x.w - c2 * T.w;
  reinterpret_cast<float4*>(out)[t] = r;
}

// ---------------------------------------------------------------------------
// Fallback if workspace too small: single pass fp32, LDS tiles, writes out.
#define TJ 64
__global__ __launch_bounds__(256) void svgd_direct_kernel(const float* __restrict__ X,
                                                          const float* __restrict__ ls,
                                                          float* __restrict__ out) {
  __shared__ float4 sX[TJ * 8];
  const int tid = threadIdx.x;
  const int row = blockIdx.x * 256 + tid;
  const float lsv = ls[0];
  const float ls2 = lsv * lsv;
  const float inv2 = 0.5f / ls2;
  float4 xi[8];
  const float4* xr = reinterpret_cast<const float4*>(X + (size_t)row * DIM);
#pragma unroll
  for (int q = 0; q < 8; ++q) xi[q] = xr[q];
  float4 acc[8];
#pragma unroll
  for (int q = 0; q < 8; ++q) acc[q] = make_float4(0.f, 0.f, 0.f, 0.f);
  float S = 0.f;
  for (int jb = 0; jb < NPART; jb += TJ) {
    __syncthreads();
    const float4* src = reinterpret_cast<const float4*>(X + (size_t)jb * DIM);
    for (int t = tid; t < TJ * 8; t += 256) sX[t] = src[t];
    __syncthreads();
    for (int t = 0; t < TJ; ++t) {
      const float4* xj = &sX[t * 8];
      float4 v[8];
      float d0 = 0.f, d1 = 0.f, d2 = 0.f, d3 = 0.f;
#pragma unroll
      for (int q = 0; q < 8; ++q) {
        v[q] = xj[q];
        float ax = xi[q].x - v[q].x; d0 = fmaf(ax, ax, d0);
        float ay = xi[q].y - v[q].y; d1 = fmaf(ay, ay, d1);
        float az = xi[q].z - v[q].z; d2 = fmaf(az, az, d2);
        float aw = xi[q].w - v[q].w; d3 = fmaf(aw, aw, d3);
      }
      float k = __expf(-((d0 + d1) + (d2 + d3)) * inv2);
      S += k;
#pragma unroll
      for (int q = 0; q < 8; ++q) {
        acc[q].x = fmaf(k, v[q].x, acc[q].x);
        acc[q].y = fmaf(k, v[q].y, acc[q].y);
        acc[q].z = fmaf(k, v[q].z, acc[q].z);
        acc[q].w = fmaf(k, v[q].w, acc[q].w);
      }
    }
  }
  const float inv = 1.f / ls2;
  const float c1 = inv * S;
  const float c2 = 1.f + inv;
  float4* o = reinterpret_cast<float4*>(out + (size_t)row * DIM);
#pragma unroll
  for (int q = 0; q < 8; ++q) {
    float4 r;
    r.x = (c1 * xi[q].x - c2 * acc[q].x) * (1.f / NPART);
    r.y = (c1 * xi[q].y - c2 * acc[q].y) * (1.f / NPART);
    r.z = (c1 * xi[q].z - c2 * acc[q].z) * (1.f / NPART);
    r.w = (c1 * xi[q].w - c2 * acc[q].w) * (1.f / NPART);
    o[q] = r;
  }
}

// ---------------------------------------------------------------------------
extern "C" void kernel_launch(void* const* d_in, const int* in_sizes, int n_in,
                              void* d_out, int out_size, void* d_ws, size_t ws_size,
                              hipStream_t stream) {
  const float* X = (const float*)d_in[0];
  const float* ls = (const float*)d_in[1];
  float* out = (float*)d_out;
  float* ws = (float*)d_ws;

  // float words: m2 4096 | XhP 65536 | XlP 65536 | XT 65536 | pT n*131072 | pS n*4096
  const size_t fixed = 4096 + 3 * 65536;
  int nsplit = 32;
  while (nsplit > 1 &&
         4 * (fixed + (size_t)nsplit * (131072 + 4096)) > ws_size) nsplit >>= 1;

  if (4 * (fixed + (size_t)(131072 + 4096)) > ws_size) {
    svgd_direct_kernel<<<NPART / 256, 256, 0, stream>>>(X, ls, out);
    return;
  }

  float* m2 = ws;
  _Float16* XhP = reinterpret_cast<_Float16*>(ws + 4096);
  _Float16* XlP = XhP + NPART * DIM;
  _Float16* XT = XlP + NPART * DIM;
  float* pT = ws + fixed;
  float* pS = pT + (size_t)nsplit * NPART * DIM;

  svgd_prep_kernel<<<NPART / 256, 256, 0, stream>>>(X, ls, m2, XhP, XlP, XT);
  dim3 grid(NPART / 128, nsplit);
  svgd_mfma_kernel<<<grid, 256, 0, stream>>>(XhP, XlP, XT, ls, m2, pT, pS,
                                             NPART / nsplit);
  svgd_reduce_kernel<<<(NPART * DIM / 4) / 128, 128, 0, stream>>>(X, ls, pT, pS,
                                                                  nsplit, out);
}

// Round 5
// 42.271 us; speedup vs baseline: 2.3798x; 1.0089x over previous
//
#include <hip/hip_runtime.h>

#define NPART 4096
#define DIM 32
#define LOG2E 1.44269504088896340736f

typedef _Float16 f16x8 __attribute__((ext_vector_type(8)));
typedef _Float16 f16x4 __attribute__((ext_vector_type(4)));
typedef float f32x4 __attribute__((ext_vector_type(4)));

// ---------------------------------------------------------------------------
// Prep: m2[r] = ||x_r||^2 * 0.5/ls^2 * log2(e)  (pre-scaled for exp2)
// XhP/XlP = hi/lo fp16 split of X in MFMA-fragment element order
// (g*8+e -> d = e<4 ? 4g+e : 16+4g+(e-4));  XT[d][j] = (f16)X[j][d].
__global__ __launch_bounds__(256) void svgd_prep_kernel(
    const float* __restrict__ X, const float* __restrict__ ls,
    float* __restrict__ m2, _Float16* __restrict__ XhP,
    _Float16* __restrict__ XlP, _Float16* __restrict__ XT) {
  const int row = blockIdx.x * 256 + threadIdx.x;
  float v[DIM];
  const float4* xr = reinterpret_cast<const float4*>(X + (size_t)row * DIM);
#pragma unroll
  for (int q = 0; q < 8; ++q) {
    float4 a = xr[q];
    v[4 * q + 0] = a.x; v[4 * q + 1] = a.y; v[4 * q + 2] = a.z; v[4 * q + 3] = a.w;
  }
  float n = 0.f;
#pragma unroll
  for (int d = 0; d < DIM; ++d) n = fmaf(v[d], v[d], n);
  const float lsv = ls[0];
  const float inv = 1.f / (lsv * lsv);
  m2[row] = n * (0.5f * inv) * LOG2E;

  _Float16 h[DIM], l[DIM];
#pragma unroll
  for (int d = 0; d < DIM; ++d) {
    h[d] = (_Float16)v[d];
    l[d] = (_Float16)(v[d] - (float)h[d]);
  }
#pragma unroll
  for (int g = 0; g < 4; ++g) {
    f16x8 ph, pl;
#pragma unroll
    for (int e = 0; e < 8; ++e) {
      int d = (e < 4) ? (4 * g + e) : (16 + 4 * g + (e - 4));
      ph[e] = h[d];
      pl[e] = l[d];
    }
    *reinterpret_cast<f16x8*>(XhP + (size_t)row * DIM + g * 8) = ph;
    *reinterpret_cast<f16x8*>(XlP + (size_t)row * DIM + g * 8) = pl;
  }
#pragma unroll
  for (int d = 0; d < DIM; ++d) XT[(size_t)d * NPART + row] = h[d];
}

// ---------------------------------------------------------------------------
// MFMA kernel, software-pipelined (double-buffered operand regs, prefetch
// next j-tile's loads before computing current). Wave owns TWO 16-row
// i-tiles; per iter: 5 loads + 10 MFMA (2 indep GEMM1 chains, 4 indep GEMM2
// chains) + 8 exp2.
__global__ __launch_bounds__(256, 4) void svgd_mfma_kernel(
    const _Float16* __restrict__ XhP, const _Float16* __restrict__ XlP,
    const _Float16* __restrict__ XT, const float* __restrict__ ls,
    const float* __restrict__ m2, float* __restrict__ pT,
    float* __restrict__ pS, int jchunk) {
  const int tid = threadIdx.x;
  const int lane = tid & 63;
  const int g = lane >> 4;    // 0..3
  const int li = lane & 15;   // 0..15
  const int wave = tid >> 6;  // 0..3
  const int i0 = blockIdx.x * 128 + wave * 32;

  const float lsv = ls[0];
  const float si2 = LOG2E / (lsv * lsv);

  // B1 fragments for 2 i-tiles
  f16x8 bh0, bl0, bh1, bl1;
  float mi0, mi1;
  {
    const int r0 = i0 + li, r1 = i0 + 16 + li;
    bh0 = *reinterpret_cast<const f16x8*>(XhP + (size_t)r0 * DIM + g * 8);
    bl0 = *reinterpret_cast<const f16x8*>(XlP + (size_t)r0 * DIM + g * 8);
    bh1 = *reinterpret_cast<const f16x8*>(XhP + (size_t)r1 * DIM + g * 8);
    bl1 = *reinterpret_cast<const f16x8*>(XlP + (size_t)r1 * DIM + g * 8);
    mi0 = m2[r0];
    mi1 = m2[r1];
  }

  f32x4 c2a0 = {0.f, 0.f, 0.f, 0.f}, c2b0 = {0.f, 0.f, 0.f, 0.f};
  f32x4 c2a1 = {0.f, 0.f, 0.f, 0.f}, c2b1 = {0.f, 0.f, 0.f, 0.f};
  float Sp0 = 0.f, Sp1 = 0.f;

  const int jbase = blockIdx.y * jchunk;
  const int niter = jchunk >> 4;

  // operand double buffers
  f16x8 Ah0, Al0, Ah1, Al1;
  f16x4 Ba0, Bb0, Ba1, Bb1;
  float4 Mj0, Mj1;

  auto LOADJ = [&](int j0, f16x8& Ah, f16x8& Al, f16x4& Ba, f16x4& Bb,
                   float4& Mj) {
    Ah = *reinterpret_cast<const f16x8*>(XhP + (size_t)(j0 + li) * DIM + g * 8);
    Al = *reinterpret_cast<const f16x8*>(XlP + (size_t)(j0 + li) * DIM + g * 8);
    Ba = *reinterpret_cast<const f16x4*>(XT + (size_t)li * NPART + j0 + 4 * g);
    Bb = *reinterpret_cast<const f16x4*>(XT + (size_t)(16 + li) * NPART + j0 + 4 * g);
    Mj = *reinterpret_cast<const float4*>(m2 + j0 + 4 * g);
  };

  auto COMP = [&](const f16x8& Ah, const f16x8& Al, const f16x4& Ba,
                  const f16x4& Bb, const float4& Mj) {
    f32x4 c10 = {0.f, 0.f, 0.f, 0.f}, c11 = {0.f, 0.f, 0.f, 0.f};
    c10 = __builtin_amdgcn_mfma_f32_16x16x32_f16(Ah, bh0, c10, 0, 0, 0);
    c11 = __builtin_amdgcn_mfma_f32_16x16x32_f16(Ah, bh1, c11, 0, 0, 0);
    c10 = __builtin_amdgcn_mfma_f32_16x16x32_f16(Al, bh0, c10, 0, 0, 0);
    c11 = __builtin_amdgcn_mfma_f32_16x16x32_f16(Al, bh1, c11, 0, 0, 0);
    c10 = __builtin_amdgcn_mfma_f32_16x16x32_f16(Ah, bl0, c10, 0, 0, 0);
    c11 = __builtin_amdgcn_mfma_f32_16x16x32_f16(Ah, bl1, c11, 0, 0, 0);
    const float mj[4] = {Mj.x, Mj.y, Mj.z, Mj.w};
    f16x4 a20, a21;
#pragma unroll
    for (int r = 0; r < 4; ++r) {
      float k0 = exp2f(fmaf(c10[r], si2, -(mi0 + mj[r])));
      float k1 = exp2f(fmaf(c11[r], si2, -(mi1 + mj[r])));
      Sp0 += k0;
      Sp1 += k1;
      a20[r] = (_Float16)k0;
      a21[r] = (_Float16)k1;
    }
    c2a0 = __builtin_amdgcn_mfma_f32_16x16x16f16(a20, Ba, c2a0, 0, 0, 0);
    c2b0 = __builtin_amdgcn_mfma_f32_16x16x16f16(a20, Bb, c2b0, 0, 0, 0);
    c2a1 = __builtin_amdgcn_mfma_f32_16x16x16f16(a21, Ba, c2a1, 0, 0, 0);
    c2b1 = __builtin_amdgcn_mfma_f32_16x16x16f16(a21, Bb, c2b1, 0, 0, 0);
  };

  LOADJ(jbase, Ah0, Al0, Ba0, Bb0, Mj0);
  for (int itr = 0; itr < niter; itr += 2) {
    const int jn1 = jbase + ((itr + 1 < niter) ? (itr + 1) * 16 : 0);
    LOADJ(jn1, Ah1, Al1, Ba1, Bb1, Mj1);
    COMP(Ah0, Al0, Ba0, Bb0, Mj0);
    const int jn2 = jbase + ((itr + 2 < niter) ? (itr + 2) * 16 : 0);
    LOADJ(jn2, Ah0, Al0, Ba0, Bb0, Mj0);
    COMP(Ah1, Al1, Ba1, Bb1, Mj1);
  }

  // store T: C2 reg r = (i = base+4g+r, d = li / 16+li)
  {
    float* base = pT + ((size_t)blockIdx.y * NPART + i0) * DIM;
#pragma unroll
    for (int r = 0; r < 4; ++r) {
      base[(4 * g + r) * DIM + li] = c2a0[r];
      base[(4 * g + r) * DIM + 16 + li] = c2b0[r];
      base[(16 + 4 * g + r) * DIM + li] = c2a1[r];
      base[(16 + 4 * g + r) * DIM + 16 + li] = c2b1[r];
    }
    float s0 = Sp0, s1 = Sp1;
    s0 += __shfl_xor(s0, 16, 64);
    s0 += __shfl_xor(s0, 32, 64);
    s1 += __shfl_xor(s1, 16, 64);
    s1 += __shfl_xor(s1, 32, 64);
    if (g == 0) {
      pS[(size_t)blockIdx.y * NPART + i0 + li] = s0;
      pS[(size_t)blockIdx.y * NPART + i0 + 16 + li] = s1;
    }
  }
}

// ---------------------------------------------------------------------------
// out[i,d] = (inv*S_i*x[i,d] - (1+inv)*T_i[d]) / N
__global__ __launch_bounds__(128) void svgd_reduce_kernel(
    const float* __restrict__ X, const float* __restrict__ ls,
    const float* __restrict__ pT, const float* __restrict__ pS, int nsplit,
    float* __restrict__ out) {
  int t = blockIdx.x * 128 + threadIdx.x;  // over N*DIM/4 float4s
  int row = t >> 3;
  const float4* pT4 = reinterpret_cast<const float4*>(pT);
  float4 T = make_float4(0.f, 0.f, 0.f, 0.f);
  float S = 0.f;
  for (int s = 0; s < nsplit; ++s) {
    float4 v = pT4[(size_t)s * (NPART * DIM / 4) + t];
    T.x += v.x; T.y += v.y; T.z += v.z; T.w += v.w;
    S += pS[(size_t)s * NPART + row];
  }
  const float lsv = ls[0];
  const float inv = 1.f / (lsv * lsv);
  const float c1 = inv * S * (1.f / NPART);
  const float c2 = (1.f + inv) * (1.f / NPART);
  float4 x = reinterpret_cast<const float4*>(X)[t];
  float4 r;
  r.x = c1 * x.x - c2 * T.x;
  r.y = c1 * x.y - c2 * T.y;
  r.z = c1 * x.z - c2 * T.z;
  r.w = c1 * x.w - c2 * T.w;
  reinterpret_cast<float4*>(out)[t] = r;
}

// ---------------------------------------------------------------------------
// Fallback if workspace too small: single pass fp32, LDS tiles, writes out.
#define TJ 64
__global__ __launch_bounds__(256) void svgd_direct_kernel(const float* __restrict__ X,
                                                          const float* __restrict__ ls,
                                                          float* __restrict__ out) {
  __shared__ float4 sX[TJ * 8];
  const int tid = threadIdx.x;
  const int row = blockIdx.x * 256 + tid;
  const float lsv = ls[0];
  const float ls2 = lsv * lsv;
  const float inv2 = 0.5f / ls2;
  float4 xi[8];
  const float4* xr = reinterpret_cast<const float4*>(X + (size_t)row * DIM);
#pragma unroll
  for (int q = 0; q < 8; ++q) xi[q] = xr[q];
  float4 acc[8];
#pragma unroll
  for (int q = 0; q < 8; ++q) acc[q] = make_float4(0.f, 0.f, 0.f, 0.f);
  float S = 0.f;
  for (int jb = 0; jb < NPART; jb += TJ) {
    __syncthreads();
    const float4* src = reinterpret_cast<const float4*>(X + (size_t)jb * DIM);
    for (int t = tid; t < TJ * 8; t += 256) sX[t] = src[t];
    __syncthreads();
    for (int t = 0; t < TJ; ++t) {
      const float4* xj = &sX[t * 8];
      float4 v[8];
      float d0 = 0.f, d1 = 0.f, d2 = 0.f, d3 = 0.f;
#pragma unroll
      for (int q = 0; q < 8; ++q) {
        v[q] = xj[q];
        float ax = xi[q].x - v[q].x; d0 = fmaf(ax, ax, d0);
        float ay = xi[q].y - v[q].y; d1 = fmaf(ay, ay, d1);
        float az = xi[q].z - v[q].z; d2 = fmaf(az, az, d2);
        float aw = xi[q].w - v[q].w; d3 = fmaf(aw, aw, d3);
      }
      float k = __expf(-((d0 + d1) + (d2 + d3)) * inv2);
      S += k;
#pragma unroll
      for (int q = 0; q < 8; ++q) {
        acc[q].x = fmaf(k, v[q].x, acc[q].x);
        acc[q].y = fmaf(k, v[q].y, acc[q].y);
        acc[q].z = fmaf(k, v[q].z, acc[q].z);
        acc[q].w = fmaf(k, v[q].w, acc[q].w);
      }
    }
  }
  const float inv = 1.f / ls2;
  const float c1 = inv * S;
  const float c2 = 1.f + inv;
  float4* o = reinterpret_cast<float4*>(out + (size_t)row * DIM);
#pragma unroll
  for (int q = 0; q < 8; ++q) {
    float4 r;
    r.x = (c1 * xi[q].x - c2 * acc[q].x) * (1.f / NPART);
    r.y = (c1 * xi[q].y - c2 * acc[q].y) * (1.f / NPART);
    r.z = (c1 * xi[q].z - c2 * acc[q].z) * (1.f / NPART);
    r.w = (c1 * xi[q].w - c2 * acc[q].w) * (1.f / NPART);
    o[q] = r;
  }
}

// ---------------------------------------------------------------------------
extern "C" void kernel_launch(void* const* d_in, const int* in_sizes, int n_in,
                              void* d_out, int out_size, void* d_ws, size_t ws_size,
                              hipStream_t stream) {
  const float* X = (const float*)d_in[0];
  const float* ls = (const float*)d_in[1];
  float* out = (float*)d_out;
  float* ws = (float*)d_ws;

  // float words: m2 4096 | XhP 65536 | XlP 65536 | XT 65536 | pT n*131072 | pS n*4096
  const size_t fixed = 4096 + 3 * 65536;
  int nsplit = 32;
  while (nsplit > 1 &&
         4 * (fixed + (size_t)nsplit * (131072 + 4096)) > ws_size) nsplit >>= 1;

  if (4 * (fixed + (size_t)(131072 + 4096)) > ws_size) {
    svgd_direct_kernel<<<NPART / 256, 256, 0, stream>>>(X, ls, out);
    return;
  }

  float* m2 = ws;
  _Float16* XhP = reinterpret_cast<_Float16*>(ws + 4096);
  _Float16* XlP = XhP + NPART * DIM;
  _Float16* XT = XlP + NPART * DIM;
  float* pT = ws + fixed;
  float* pS = pT + (size_t)nsplit * NPART * DIM;

  svgd_prep_kernel<<<NPART / 256, 256, 0, stream>>>(X, ls, m2, XhP, XlP, XT);
  dim3 grid(NPART / 128, nsplit);
  svgd_mfma_kernel<<<grid, 256, 0, stream>>>(XhP, XlP, XT, ls, m2, pT, pS,
                                             NPART / nsplit);
  svgd_reduce_kernel<<<(NPART * DIM / 4) / 128, 128, 0, stream>>>(X, ls, pT, pS,
                                                                  nsplit, out);
}

// Round 6
// 27.291 us; speedup vs baseline: 3.6861x; 1.5489x over previous
//
#include <hip/hip_runtime.h>

#define NPART 4096
#define DIM 32
#define LOG2E 1.44269504088896340736f

typedef _Float16 f16x8 __attribute__((ext_vector_type(8)));
typedef _Float16 f16x4 __attribute__((ext_vector_type(4)));
typedef float f32x4 __attribute__((ext_vector_type(4)));

// ---------------------------------------------------------------------------
// Prep: zero out; m2[r] = ||x_r||^2 * 0.5/ls^2 * log2e; XhP/XlP = hi/lo fp16
// split of X in MFMA-fragment order (g*8+e -> d = e<4 ? 4g+e : 16+4g+e-4);
// XT[d][j] = (f16)X[j][d].
__global__ __launch_bounds__(256) void svgd_prep_kernel(
    const float* __restrict__ X, const float* __restrict__ ls,
    float* __restrict__ m2, _Float16* __restrict__ XhP,
    _Float16* __restrict__ XlP, _Float16* __restrict__ XT,
    float* __restrict__ out) {
  const int row = blockIdx.x * 256 + threadIdx.x;  // 4096 threads total

  // zero the output (poisoned 0xAA by harness; atomics accumulate into it)
  {
    float4 z = make_float4(0.f, 0.f, 0.f, 0.f);
    float4* o4 = reinterpret_cast<float4*>(out);
#pragma unroll
    for (int q = 0; q < 8; ++q) o4[(size_t)q * 4096 + row] = z;
  }

  float v[DIM];
  const float4* xr = reinterpret_cast<const float4*>(X + (size_t)row * DIM);
#pragma unroll
  for (int q = 0; q < 8; ++q) {
    float4 a = xr[q];
    v[4 * q + 0] = a.x; v[4 * q + 1] = a.y; v[4 * q + 2] = a.z; v[4 * q + 3] = a.w;
  }
  float n = 0.f;
#pragma unroll
  for (int d = 0; d < DIM; ++d) n = fmaf(v[d], v[d], n);
  const float lsv = ls[0];
  const float inv = 1.f / (lsv * lsv);
  m2[row] = n * (0.5f * inv) * LOG2E;

  _Float16 h[DIM], l[DIM];
#pragma unroll
  for (int d = 0; d < DIM; ++d) {
    h[d] = (_Float16)v[d];
    l[d] = (_Float16)(v[d] - (float)h[d]);
  }
#pragma unroll
  for (int g = 0; g < 4; ++g) {
    f16x8 ph, pl;
#pragma unroll
    for (int e = 0; e < 8; ++e) {
      int d = (e < 4) ? (4 * g + e) : (16 + 4 * g + (e - 4));
      ph[e] = h[d];
      pl[e] = l[d];
    }
    *reinterpret_cast<f16x8*>(XhP + (size_t)row * DIM + g * 8) = ph;
    *reinterpret_cast<f16x8*>(XlP + (size_t)row * DIM + g * 8) = pl;
  }
#pragma unroll
  for (int d = 0; d < DIM; ++d) XT[(size_t)d * NPART + row] = h[d];
}

// ---------------------------------------------------------------------------
// Fused main: block = one 32-row i-tile (all 4 waves) x one 512-col j-chunk
// (split 4 ways across waves). Per-wave inner loop identical to R5 (verified
// layouts). Block-level reduce of T,S through LDS; one atomicAdd pass of the
// linear contribution into out.
__global__ __launch_bounds__(256, 4) void svgd_fused_kernel(
    const float* __restrict__ X, const _Float16* __restrict__ XhP,
    const _Float16* __restrict__ XlP, const _Float16* __restrict__ XT,
    const float* __restrict__ ls, const float* __restrict__ m2,
    float* __restrict__ out) {
  __shared__ float sT[4][32][32];
  __shared__ float sS[4][32];

  const int tid = threadIdx.x;
  const int lane = tid & 63;
  const int g = lane >> 4;    // 0..3
  const int li = lane & 15;   // 0..15
  const int wave = tid >> 6;  // 0..3
  const int i0 = blockIdx.x * 32;
  const int jbase = blockIdx.y * 512 + wave * 128;

  const float lsv = ls[0];
  const float si2 = LOG2E / (lsv * lsv);

  // B1 fragments for the 2 i-subtiles (same for all 4 waves)
  f16x8 bh0, bl0, bh1, bl1;
  float mi0, mi1;
  {
    const int r0 = i0 + li, r1 = i0 + 16 + li;
    bh0 = *reinterpret_cast<const f16x8*>(XhP + (size_t)r0 * DIM + g * 8);
    bl0 = *reinterpret_cast<const f16x8*>(XlP + (size_t)r0 * DIM + g * 8);
    bh1 = *reinterpret_cast<const f16x8*>(XhP + (size_t)r1 * DIM + g * 8);
    bl1 = *reinterpret_cast<const f16x8*>(XlP + (size_t)r1 * DIM + g * 8);
    mi0 = m2[r0];
    mi1 = m2[r1];
  }

  f32x4 c2a0 = {0.f, 0.f, 0.f, 0.f}, c2b0 = {0.f, 0.f, 0.f, 0.f};
  f32x4 c2a1 = {0.f, 0.f, 0.f, 0.f}, c2b1 = {0.f, 0.f, 0.f, 0.f};
  float Sp0 = 0.f, Sp1 = 0.f;

  // operand double buffers
  f16x8 Ah0, Al0, Ah1, Al1;
  f16x4 Ba0, Bb0, Ba1, Bb1;
  float4 Mj0, Mj1;

  auto LOADJ = [&](int j0, f16x8& Ah, f16x8& Al, f16x4& Ba, f16x4& Bb,
                   float4& Mj) {
    Ah = *reinterpret_cast<const f16x8*>(XhP + (size_t)(j0 + li) * DIM + g * 8);
    Al = *reinterpret_cast<const f16x8*>(XlP + (size_t)(j0 + li) * DIM + g * 8);
    Ba = *reinterpret_cast<const f16x4*>(XT + (size_t)li * NPART + j0 + 4 * g);
    Bb = *reinterpret_cast<const f16x4*>(XT + (size_t)(16 + li) * NPART + j0 + 4 * g);
    Mj = *reinterpret_cast<const float4*>(m2 + j0 + 4 * g);
  };

  auto COMP = [&](const f16x8& Ah, const f16x8& Al, const f16x4& Ba,
                  const f16x4& Bb, const float4& Mj) {
    f32x4 c10 = {0.f, 0.f, 0.f, 0.f}, c11 = {0.f, 0.f, 0.f, 0.f};
    c10 = __builtin_amdgcn_mfma_f32_16x16x32_f16(Ah, bh0, c10, 0, 0, 0);
    c11 = __builtin_amdgcn_mfma_f32_16x16x32_f16(Ah, bh1, c11, 0, 0, 0);
    c10 = __builtin_amdgcn_mfma_f32_16x16x32_f16(Al, bh0, c10, 0, 0, 0);
    c11 = __builtin_amdgcn_mfma_f32_16x16x32_f16(Al, bh1, c11, 0, 0, 0);
    c10 = __builtin_amdgcn_mfma_f32_16x16x32_f16(Ah, bl0, c10, 0, 0, 0);
    c11 = __builtin_amdgcn_mfma_f32_16x16x32_f16(Ah, bl1, c11, 0, 0, 0);
    const float mj[4] = {Mj.x, Mj.y, Mj.z, Mj.w};
    f16x4 a20, a21;
#pragma unroll
    for (int r = 0; r < 4; ++r) {
      float k0 = exp2f(fmaf(c10[r], si2, -(mi0 + mj[r])));
      float k1 = exp2f(fmaf(c11[r], si2, -(mi1 + mj[r])));
      Sp0 += k0;
      Sp1 += k1;
      a20[r] = (_Float16)k0;
      a21[r] = (_Float16)k1;
    }
    c2a0 = __builtin_amdgcn_mfma_f32_16x16x16f16(a20, Ba, c2a0, 0, 0, 0);
    c2b0 = __builtin_amdgcn_mfma_f32_16x16x16f16(a20, Bb, c2b0, 0, 0, 0);
    c2a1 = __builtin_amdgcn_mfma_f32_16x16x16f16(a21, Ba, c2a1, 0, 0, 0);
    c2b1 = __builtin_amdgcn_mfma_f32_16x16x16f16(a21, Bb, c2b1, 0, 0, 0);
  };

  LOADJ(jbase, Ah0, Al0, Ba0, Bb0, Mj0);
#pragma unroll
  for (int itr = 0; itr < 8; itr += 2) {
    LOADJ(jbase + (itr + 1) * 16, Ah1, Al1, Ba1, Bb1, Mj1);
    COMP(Ah0, Al0, Ba0, Bb0, Mj0);
    const int jn2 = jbase + ((itr + 2 < 8) ? (itr + 2) * 16 : 0);
    LOADJ(jn2, Ah0, Al0, Ba0, Bb0, Mj0);
    COMP(Ah1, Al1, Ba1, Bb1, Mj1);
  }

  // per-wave partials -> LDS
#pragma unroll
  for (int r = 0; r < 4; ++r) {
    sT[wave][4 * g + r][li] = c2a0[r];
    sT[wave][4 * g + r][16 + li] = c2b0[r];
    sT[wave][16 + 4 * g + r][li] = c2a1[r];
    sT[wave][16 + 4 * g + r][16 + li] = c2b1[r];
  }
  {
    float s0 = Sp0, s1 = Sp1;
    s0 += __shfl_xor(s0, 16, 64);
    s0 += __shfl_xor(s0, 32, 64);
    s1 += __shfl_xor(s1, 16, 64);
    s1 += __shfl_xor(s1, 32, 64);
    if (g == 0) {
      sS[wave][li] = s0;
      sS[wave][16 + li] = s1;
    }
  }
  __syncthreads();

  // block contribution -> out (atomic, linear in (S,T))
  const float inv = si2 * (1.f / LOG2E);
  const float c1f = inv * (1.f / NPART);
  const float c2f = (1.f + inv) * (1.f / NPART);
#pragma unroll
  for (int q = 0; q < 4; ++q) {
    const int v = q * 256 + tid;
    const int row = v >> 5, d = v & 31;
    const float T = sT[0][row][d] + sT[1][row][d] + sT[2][row][d] + sT[3][row][d];
    const float S = sS[0][row] + sS[1][row] + sS[2][row] + sS[3][row];
    const size_t idx = (size_t)(i0 + row) * DIM + d;
    unsafeAtomicAdd(&out[idx], c1f * S * X[idx] - c2f * T);
  }
}

// ---------------------------------------------------------------------------
// Fallback if workspace too small: single pass fp32, LDS tiles, writes out.
#define TJ 64
__global__ __launch_bounds__(256) void svgd_direct_kernel(const float* __restrict__ X,
                                                          const float* __restrict__ ls,
                                                          float* __restrict__ out) {
  __shared__ float4 sX[TJ * 8];
  const int tid = threadIdx.x;
  const int row = blockIdx.x * 256 + tid;
  const float lsv = ls[0];
  const float ls2 = lsv * lsv;
  const float inv2 = 0.5f / ls2;
  float4 xi[8];
  const float4* xr = reinterpret_cast<const float4*>(X + (size_t)row * DIM);
#pragma unroll
  for (int q = 0; q < 8; ++q) xi[q] = xr[q];
  float4 acc[8];
#pragma unroll
  for (int q = 0; q < 8; ++q) acc[q] = make_float4(0.f, 0.f, 0.f, 0.f);
  float S = 0.f;
  for (int jb = 0; jb < NPART; jb += TJ) {
    __syncthreads();
    const float4* src = reinterpret_cast<const float4*>(X + (size_t)jb * DIM);
    for (int t = tid; t < TJ * 8; t += 256) sX[t] = src[t];
    __syncthreads();
    for (int t = 0; t < TJ; ++t) {
      const float4* xj = &sX[t * 8];
      float4 v[8];
      float d0 = 0.f, d1 = 0.f, d2 = 0.f, d3 = 0.f;
#pragma unroll
      for (int q = 0; q < 8; ++q) {
        v[q] = xj[q];
        float ax = xi[q].x - v[q].x; d0 = fmaf(ax, ax, d0);
        float ay = xi[q].y - v[q].y; d1 = fmaf(ay, ay, d1);
        float az = xi[q].z - v[q].z; d2 = fmaf(az, az, d2);
        float aw = xi[q].w - v[q].w; d3 = fmaf(aw, aw, d3);
      }
      float k = __expf(-((d0 + d1) + (d2 + d3)) * inv2);
      S += k;
#pragma unroll
      for (int q = 0; q < 8; ++q) {
        acc[q].x = fmaf(k, v[q].x, acc[q].x);
        acc[q].y = fmaf(k, v[q].y, acc[q].y);
        acc[q].z = fmaf(k, v[q].z, acc[q].z);
        acc[q].w = fmaf(k, v[q].w, acc[q].w);
      }
    }
  }
  const float inv = 1.f / ls2;
  const float c1 = inv * S;
  const float c2 = 1.f + inv;
  float4* o = reinterpret_cast<float4*>(out + (size_t)row * DIM);
#pragma unroll
  for (int q = 0; q < 8; ++q) {
    float4 r;
    r.x = (c1 * xi[q].x - c2 * acc[q].x) * (1.f / NPART);
    r.y = (c1 * xi[q].y - c2 * acc[q].y) * (1.f / NPART);
    r.z = (c1 * xi[q].z - c2 * acc[q].z) * (1.f / NPART);
    r.w = (c1 * xi[q].w - c2 * acc[q].w) * (1.f / NPART);
    o[q] = r;
  }
}

// ---------------------------------------------------------------------------
extern "C" void kernel_launch(void* const* d_in, const int* in_sizes, int n_in,
                              void* d_out, int out_size, void* d_ws, size_t ws_size,
                              hipStream_t stream) {
  const float* X = (const float*)d_in[0];
  const float* ls = (const float*)d_in[1];
  float* out = (float*)d_out;
  float* ws = (float*)d_ws;

  // float words: m2 4096 | XhP 65536 | XlP 65536 | XT 65536
  const size_t fixed = 4096 + 3 * 65536;
  if (4 * fixed > ws_size) {
    svgd_direct_kernel<<<NPART / 256, 256, 0, stream>>>(X, ls, out);
    return;
  }

  float* m2 = ws;
  _Float16* XhP = reinterpret_cast<_Float16*>(ws + 4096);
  _Float16* XlP = XhP + NPART * DIM;
  _Float16* XT = XlP + NPART * DIM;

  svgd_prep_kernel<<<NPART / 256, 256, 0, stream>>>(X, ls, m2, XhP, XlP, XT, out);
  dim3 grid(NPART / 32, 8);
  svgd_fused_kernel<<<grid, 256, 0, stream>>>(X, XhP, XlP, XT, ls, m2, out);
}